// Round 3
// baseline (1231.569 us; speedup 1.0000x reference)
//
#include <hip/hip_runtime.h>
#include <cmath>

typedef unsigned short u16;
typedef __attribute__((ext_vector_type(8))) short v8s;
typedef __attribute__((ext_vector_type(4))) float f32x4;

#define NBATCH 8
#define SEQ 4096
#define CH 896
#define NC ((size_t)SEQ * CH)     /* 3670016 elems per batch */

__device__ __forceinline__ float b2f(u16 u) {
  unsigned v = ((unsigned)u) << 16;
  return __builtin_bit_cast(float, v);
}
__device__ __forceinline__ u16 f2b(float f) {
  unsigned u = __builtin_bit_cast(unsigned, f);
  u += 0x7FFFu + ((u >> 16) & 1u);   // RNE
  return (u16)(u >> 16);
}

__device__ __forceinline__ f32x4 mfma16(v8s a, v8s b, f32x4 c) {
  asm("v_mfma_f32_16x16x32_bf16 %0, %1, %2, %0" : "+v"(c) : "v"(a), "v"(b));
  return c;
}

// ---------------- fp32 -> bf16 convert (8 elems/thread, exact-sized grid) ----
__launch_bounds__(256)
__global__ void cvt_k(const float* __restrict__ in, u16* __restrict__ out)
{
  const size_t i = ((size_t)blockIdx.x * 256 + threadIdx.x) * 8;
  const float4 a = *(const float4*)(in + i);
  const float4 b = *(const float4*)(in + i + 4);
  union { v8s v; u16 u[8]; } o;
  o.u[0] = f2b(a.x); o.u[1] = f2b(a.y); o.u[2] = f2b(a.z); o.u[3] = f2b(a.w);
  o.u[4] = f2b(b.x); o.u[5] = f2b(b.y); o.u[6] = f2b(b.z); o.u[7] = f2b(b.w);
  *(v8s*)(out + i) = o.v;
}

// ---------------- bf16 MFMA NT-GEMM, 128x128 tile, BK=32, 4 waves -----------
// D[i][j] = sum_k A[i][k] * B[j][k]   (both A,B row-major [rows][896])
// MODE 0: store bf16 D row-major ld=896 (y = x @ M)
// MODE 1: E = exp(D) bf16 ld=4096 (slab-local rows), atomic row sums -> lsum
// MODE 2: store bf16 scale*D TRANSPOSED ld=896 (mt = (scale*Wq@Wk^T)^T)
template<int MODE>
__launch_bounds__(256)
__global__ void gemm_k(const u16* __restrict__ A, const u16* __restrict__ B,
                       u16* __restrict__ outp, float* __restrict__ lsum, float scale)
{
  __shared__ __align__(16) u16 As[128][40];  // +8 u16 pad: 80B rows, <=2-way LDS conflicts
  __shared__ __align__(16) u16 Bs[128][40];
  const int tid  = threadIdx.x;
  const int lane = tid & 63;
  const int wv   = tid >> 6;
  const int wr   = (wv >> 1) * 64;
  const int wc   = (wv & 1) * 64;
  const int row0 = blockIdx.x * 128;
  const int col0 = blockIdx.y * 128;
  const int srow = tid >> 2;        // 0..63
  const int sk   = (tid & 3) * 8;   // 0,8,16,24
  const u16* ag = A + (size_t)(row0 + srow) * CH + sk;
  const u16* bg = B + (size_t)(col0 + srow) * CH + sk;

  f32x4 acc[4][4];
  #pragma unroll
  for (int i = 0; i < 4; i++)
    #pragma unroll
    for (int j = 0; j < 4; j++)
      acc[i][j] = f32x4{0.f, 0.f, 0.f, 0.f};

  const int lo = lane & 15, hi = lane >> 4;
  const int kk = hi * 8;

  for (int k0 = 0; k0 < CH; k0 += 32) {
    __syncthreads();
    *(v8s*)(&As[srow][sk])      = *(const v8s*)(ag + k0);
    *(v8s*)(&As[srow + 64][sk]) = *(const v8s*)(ag + (size_t)64 * CH + k0);
    *(v8s*)(&Bs[srow][sk])      = *(const v8s*)(bg + k0);
    *(v8s*)(&Bs[srow + 64][sk]) = *(const v8s*)(bg + (size_t)64 * CH + k0);
    __syncthreads();
    v8s af[4], bf[4];
    #pragma unroll
    for (int f = 0; f < 4; f++) af[f] = *(const v8s*)(&As[wr + lo + f * 16][kk]);
    #pragma unroll
    for (int f = 0; f < 4; f++) bf[f] = *(const v8s*)(&Bs[wc + lo + f * 16][kk]);
    #pragma unroll
    for (int i = 0; i < 4; i++)
      #pragma unroll
      for (int j = 0; j < 4; j++)
        acc[i][j] = mfma16(af[i], bf[j], acc[i][j]);
  }
  __builtin_amdgcn_sched_barrier(0);
  asm volatile("s_nop 7\ns_nop 7\ns_nop 7");   // MFMA->VALU read hazard guard
  __builtin_amdgcn_sched_barrier(0);

  if constexpr (MODE == 0) {
    #pragma unroll
    for (int i = 0; i < 4; i++)
      #pragma unroll
      for (int j = 0; j < 4; j++) {
        const int col = col0 + wc + j * 16 + lo;
        #pragma unroll
        for (int r = 0; r < 4; r++) {
          const int row = row0 + wr + i * 16 + hi * 4 + r;
          outp[(size_t)row * CH + col] = f2b(acc[i][j][r]);
        }
      }
  } else if constexpr (MODE == 1) {
    float rsum[4][4];
    #pragma unroll
    for (int i = 0; i < 4; i++)
      #pragma unroll
      for (int r = 0; r < 4; r++) rsum[i][r] = 0.f;
    #pragma unroll
    for (int i = 0; i < 4; i++)
      #pragma unroll
      for (int j = 0; j < 4; j++) {
        const int col = col0 + wc + j * 16 + lo;
        #pragma unroll
        for (int r = 0; r < 4; r++) {
          const float e = __expf(acc[i][j][r]);
          rsum[i][r] += e;
          const int row = row0 + wr + i * 16 + hi * 4 + r;
          outp[(size_t)row * SEQ + col] = f2b(e);
        }
      }
    #pragma unroll
    for (int msk = 1; msk < 16; msk <<= 1)
      #pragma unroll
      for (int i = 0; i < 4; i++)
        #pragma unroll
        for (int r = 0; r < 4; r++)
          rsum[i][r] += __shfl_xor(rsum[i][r], msk, 64);
    if (lo == 0) {
      #pragma unroll
      for (int i = 0; i < 4; i++)
        #pragma unroll
        for (int r = 0; r < 4; r++)
          atomicAdd(&lsum[row0 + wr + i * 16 + hi * 4 + r], rsum[i][r]);
    }
  } else {
    #pragma unroll
    for (int i = 0; i < 4; i++)
      #pragma unroll
      for (int j = 0; j < 4; j++) {
        const int col = col0 + wc + j * 16 + lo;
        #pragma unroll
        for (int r = 0; r < 4; r++) {
          const int row = row0 + wr + i * 16 + hi * 4 + r;
          outp[(size_t)col * CH + row] = f2b(acc[i][j][r] * scale);
        }
      }
  }
}

// ---------------- rl = 1/l ---------------------------------------------------
__launch_bounds__(256)
__global__ void rl_k(const float* __restrict__ l, float* __restrict__ rl, int n)
{
  const int i = blockIdx.x * 256 + threadIdx.x;
  if (i < n) rl[i] = 1.0f / l[i];
}

// ---------------- w[m] += sum_n E[n,m] * rl[n]  (softmax column sums) --------
// grid (R/128, 2): each block does 128 n-rows x 2048 m-cols, 8 m per thread.
__launch_bounds__(256)
__global__ void w_k(const u16* __restrict__ E, const float* __restrict__ rl,
                    float* __restrict__ w)
{
  const int m0 = (blockIdx.y * 256 + threadIdx.x) * 8;
  const int n0 = blockIdx.x * 128;
  float acc[8] = {0.f, 0.f, 0.f, 0.f, 0.f, 0.f, 0.f, 0.f};
  for (int n = 0; n < 128; n++) {
    const float r = rl[n0 + n];
    union { v8s v; u16 u[8]; } e;
    e.v = *(const v8s*)(E + (size_t)(n0 + n) * SEQ + m0);
    #pragma unroll
    for (int u = 0; u < 8; u++) acc[u] = fmaf(b2f(e.u[u]), r, acc[u]);
  }
  #pragma unroll
  for (int u = 0; u < 8; u++) atomicAdd(&w[m0 + u], acc[u]);
}

// ---------------- s = (1/N) w^T x ; mx = mean_n x ---------------------------
__launch_bounds__(256)
__global__ void sx_k(const float* __restrict__ x, const float* __restrict__ w,
                     float* __restrict__ s, float* __restrict__ mx)
{
  const int b  = blockIdx.x;
  const int c  = blockIdx.y * 256 + threadIdx.x;
  const int m0 = blockIdx.z * 256;
  if (c >= CH) return;
  const float* xb = x + (size_t)b * NC;
  const float* wb = w + b * SEQ;
  float sw = 0.f, sxv = 0.f;
  for (int m = m0; m < m0 + 256; m++) {
    const float xv = xb[(size_t)m * CH + c];
    sw  = fmaf(wb[m], xv, sw);
    sxv += xv;
  }
  const float inv = 1.0f / (float)SEQ;
  atomicAdd(&s[b * CH + c], sw * inv);
  atomicAdd(&mx[b * CH + c], sxv * inv);
}

// ---------------- tail: pooled = s@Wv@Wp + bp + mx; FFN ----------------------
__launch_bounds__(896)
__global__ void tail_k(const float* __restrict__ s, const float* __restrict__ mx,
                       const float* __restrict__ Wv, const float* __restrict__ Wp,
                       const float* __restrict__ bp, const float* __restrict__ Wf1,
                       const float* __restrict__ bf1, const float* __restrict__ Wf2,
                       const float* __restrict__ bf2, float* __restrict__ out)
{
  const int b = blockIdx.x, t = threadIdx.x;
  __shared__ float v0[CH], v1[CH];
  v0[t] = s[b * CH + t];
  __syncthreads();
  float a = 0.f;
  #pragma unroll 8
  for (int e = 0; e < CH; e++) a = fmaf(v0[e], Wv[e * CH + t], a);
  v1[t] = a;                       // mean attention output (pre-Wp)
  __syncthreads();
  a = 0.f;
  #pragma unroll 8
  for (int e = 0; e < CH; e++) a = fmaf(v1[e], Wp[e * CH + t], a);
  v0[t] = a + bp[t] + mx[b * CH + t];   // pooled
  __syncthreads();
  a = 0.f;
  #pragma unroll 8
  for (int e = 0; e < CH; e++) a = fmaf(v0[e], Wf1[e * CH + t], a);
  v1[t] = fmaxf(a + bf1[t], 0.f);       // h = relu(...)
  __syncthreads();
  a = 0.f;
  #pragma unroll 8
  for (int e = 0; e < CH; e++) a = fmaf(v1[e], Wf2[e * CH + t], a);
  out[b * CH + t] = a + bf2[t];
}

// ---------------- host -------------------------------------------------------
// Workspace layout (floor ~21 MB; E slab adapts to remaining ws):
//   [0,131072)          l_   (8*4096 f32, atomic row sums)        — memset 0
//   [131072,262144)     w_   (8*4096 f32, atomic col sums)        — memset 0
//   [262144,290816)     s_   (8*896 f32)                          — memset 0
//   [290816,319488)     mx_  (8*896 f32)                          — memset 0
//   [319488,450560)     rl_  (8*4096 f32)
//   [450560,2056192)    wqb  (bf16 Wq)
//   [2056192,3661824)   wkb  (bf16 Wk)
//   [3661824,5267456)   mt   (bf16 M^T, M = scale*Wq@Wk^T)
//   [5267456,12607488)  xb   (bf16 x, ONE batch)
//   [12607488,19947520) yb   (bf16 y = x@M, ONE batch)
//   [19947520,...)      E    (bf16 exp(S) slab, R rows x 4096)
extern "C" void kernel_launch(void* const* d_in, const int* in_sizes, int n_in,
                              void* d_out, int out_size, void* d_ws, size_t ws_size,
                              hipStream_t stream)
{
  (void)in_sizes; (void)n_in; (void)out_size;
  const float* x   = (const float*)d_in[0];
  const float* Wq  = (const float*)d_in[1];
  const float* Wk  = (const float*)d_in[2];
  const float* Wv  = (const float*)d_in[3];
  const float* Wp  = (const float*)d_in[4];
  const float* bp  = (const float*)d_in[5];
  const float* Wf1 = (const float*)d_in[6];
  const float* bf1 = (const float*)d_in[7];
  const float* Wf2 = (const float*)d_in[8];
  const float* bf2 = (const float*)d_in[9];
  float* out = (float*)d_out;

  char* ws = (char*)d_ws;
  float* l_  = (float*)(ws + 0);
  float* w_  = (float*)(ws + 131072);
  float* s_  = (float*)(ws + 262144);
  float* mx_ = (float*)(ws + 290816);
  float* rl_ = (float*)(ws + 319488);
  u16* wqb = (u16*)(ws + 450560);
  u16* wkb = (u16*)(ws + 2056192);
  u16* mt  = (u16*)(ws + 3661824);
  u16* xb  = (u16*)(ws + 5267456);
  u16* yb  = (u16*)(ws + 12607488);
  u16* eb  = (u16*)(ws + 19947520);

  // E slab rows: as many 128-row blocks as fit in the remaining workspace
  const size_t ecap = ws_size > 19947520ULL ? ws_size - 19947520ULL : 0;
  int R = (int)(ecap / ((size_t)SEQ * 2) / 128) * 128;
  if (R > SEQ) R = SEQ;
  if (R < 128) R = 128;   // below this we cannot run; assume ws >= ~21MB

  // zero the atomically-accumulated buffers (ws is poisoned before every call)
  hipMemsetAsync(d_ws, 0, 319488, stream);

  cvt_k<<<392, 256, 0, stream>>>(Wq, wqb);
  cvt_k<<<392, 256, 0, stream>>>(Wk, wkb);
  const float scale = 1.0f / sqrtf((float)CH);
  // mt = (scale * Wq @ Wk^T)^T
  gemm_k<2><<<dim3(7, 7), 256, 0, stream>>>(wqb, wkb, mt, nullptr, scale);

  for (int b = 0; b < NBATCH; b++) {
    cvt_k<<<1792, 256, 0, stream>>>(x + (size_t)b * NC, xb);
    // y_b = x_b @ M (mt rows are k-contiguous)
    gemm_k<0><<<dim3(32, 7), 256, 0, stream>>>(xb, mt, yb, nullptr, 1.f);
    for (int n0 = 0; n0 < SEQ; n0 += R) {
      const int rows = (SEQ - n0) < R ? (SEQ - n0) : R;
      // E = exp(y_b[n0:n0+rows] @ x_b^T), row sums -> l
      gemm_k<1><<<dim3(rows / 128, 32), 256, 0, stream>>>(
          yb + (size_t)n0 * CH, xb, eb, l_ + b * SEQ + n0, 1.f);
      rl_k<<<(rows + 255) / 256, 256, 0, stream>>>(
          l_ + b * SEQ + n0, rl_ + b * SEQ + n0, rows);
      w_k<<<dim3(rows / 128, 2), 256, 0, stream>>>(
          eb, rl_ + b * SEQ + n0, w_ + b * SEQ);
    }
  }

  sx_k<<<dim3(8, 4, 16), 256, 0, stream>>>(x, w_, s_, mx_);
  tail_k<<<8, 896, 0, stream>>>(s_, mx_, Wv, Wp, bp, Wf1, bf1, Wf2, bf2, out);
}

// Round 4
// 950.830 us; speedup vs baseline: 1.2953x; 1.2953x over previous
//
#include <hip/hip_runtime.h>
#include <cmath>

typedef unsigned short u16;
typedef __attribute__((ext_vector_type(8))) short v8s;
typedef __attribute__((ext_vector_type(4))) float f32x4;

#define NBATCH 8
#define SEQ 4096
#define CH 896
#define NC ((size_t)SEQ * CH)     /* 3670016 elems per batch */

__device__ __forceinline__ float b2f(u16 u) {
  unsigned v = ((unsigned)u) << 16;
  return __builtin_bit_cast(float, v);
}
__device__ __forceinline__ u16 f2b(float f) {
  unsigned u = __builtin_bit_cast(unsigned, f);
  u += 0x7FFFu + ((u >> 16) & 1u);   // RNE
  return (u16)(u >> 16);
}

__device__ __forceinline__ f32x4 mfma16(v8s a, v8s b, f32x4 c) {
  asm("v_mfma_f32_16x16x32_bf16 %0, %1, %2, %0" : "+v"(c) : "v"(a), "v"(b));
  return c;
}

// async global->LDS DMA, 16B per lane (global_load_lds_dwordx4)
__device__ __forceinline__ void gload16(const u16* g, u16* l) {
  __builtin_amdgcn_global_load_lds(
      (const __attribute__((address_space(1))) unsigned int*)g,
      (__attribute__((address_space(3))) unsigned int*)l, 16, 0, 0);
}

// ---------------- fp32 -> bf16 convert (8 elems/thread, exact-sized grid) ----
__launch_bounds__(256)
__global__ void cvt_k(const float* __restrict__ in, u16* __restrict__ out)
{
  const size_t i = ((size_t)blockIdx.x * 256 + threadIdx.x) * 8;
  const float4 a = *(const float4*)(in + i);
  const float4 b = *(const float4*)(in + i + 4);
  union { v8s v; u16 u[8]; } o;
  o.u[0] = f2b(a.x); o.u[1] = f2b(a.y); o.u[2] = f2b(a.z); o.u[3] = f2b(a.w);
  o.u[4] = f2b(b.x); o.u[5] = f2b(b.y); o.u[6] = f2b(b.z); o.u[7] = f2b(b.w);
  *(v8s*)(out + i) = o.v;
}

// ---------------- bf16 MFMA NT-GEMM, 128x128 tile, BK=32, 4 waves -----------
// D[i][j] = sum_k A[i][k] * B[j][k]   (both A,B row-major [rows][896])
// Staging via global_load_lds width=16 into LINEAR LDS [128][32] (no pad).
// MODE 0: store bf16 D row-major ld=896 (y = x @ M)
// MODE 1: E = exp(D) bf16 ld=4096 (slab-local rows), atomic row sums -> lsum
// MODE 2: store bf16 scale*D TRANSPOSED ld=896 (mt = (scale*Wq@Wk^T)^T)
template<int MODE>
__launch_bounds__(256)
__global__ void gemm_k(const u16* __restrict__ A, const u16* __restrict__ B,
                       u16* __restrict__ outp, float* __restrict__ lsum, float scale)
{
  __shared__ __align__(16) u16 As[128 * 32];
  __shared__ __align__(16) u16 Bs[128 * 32];
  const int tid  = threadIdx.x;
  const int lane = tid & 63;
  const int wv   = tid >> 6;
  const int wr   = (wv >> 1) * 64;
  const int wc   = (wv & 1) * 64;
  const int row0 = blockIdx.x * 128;
  const int col0 = blockIdx.y * 128;
  const int srow = tid >> 2;        // 0..63
  const int sk   = (tid & 3) * 8;   // 0,8,16,24
  const u16* ag = A + (size_t)(row0 + srow) * CH + sk;
  const u16* bg = B + (size_t)(col0 + srow) * CH + sk;
  u16* asd = As + tid * 8;          // linear DMA dest: row-major [row][k]
  u16* bsd = Bs + tid * 8;          //   (t*8 == (t>>2)*32 + (t&3)*8)

  f32x4 acc[4][4];
  #pragma unroll
  for (int i = 0; i < 4; i++)
    #pragma unroll
    for (int j = 0; j < 4; j++)
      acc[i][j] = f32x4{0.f, 0.f, 0.f, 0.f};

  const int lo = lane & 15, hi = lane >> 4;
  const int kk = hi * 8;

  for (int k0 = 0; k0 < CH; k0 += 32) {
    __syncthreads();                     // prev tile's ds_reads all consumed
    gload16(ag + k0, asd);
    gload16(ag + (size_t)64 * CH + k0, asd + 64 * 32);
    gload16(bg + k0, bsd);
    gload16(bg + (size_t)64 * CH + k0, bsd + 64 * 32);
    __syncthreads();                     // compiler drains vmcnt before barrier
    v8s af[4], bf[4];
    #pragma unroll
    for (int f = 0; f < 4; f++) af[f] = *(const v8s*)(As + (wr + lo + f * 16) * 32 + kk);
    #pragma unroll
    for (int f = 0; f < 4; f++) bf[f] = *(const v8s*)(Bs + (wc + lo + f * 16) * 32 + kk);
    #pragma unroll
    for (int i = 0; i < 4; i++)
      #pragma unroll
      for (int j = 0; j < 4; j++)
        acc[i][j] = mfma16(af[i], bf[j], acc[i][j]);
  }
  __builtin_amdgcn_sched_barrier(0);
  asm volatile("s_nop 7\ns_nop 7\ns_nop 7");   // MFMA->VALU read hazard guard
  __builtin_amdgcn_sched_barrier(0);

  if constexpr (MODE == 0) {
    #pragma unroll
    for (int i = 0; i < 4; i++)
      #pragma unroll
      for (int j = 0; j < 4; j++) {
        const int col = col0 + wc + j * 16 + lo;
        #pragma unroll
        for (int r = 0; r < 4; r++) {
          const int row = row0 + wr + i * 16 + hi * 4 + r;
          outp[(size_t)row * CH + col] = f2b(acc[i][j][r]);
        }
      }
  } else if constexpr (MODE == 1) {
    float rsum[4][4];
    #pragma unroll
    for (int i = 0; i < 4; i++)
      #pragma unroll
      for (int r = 0; r < 4; r++) rsum[i][r] = 0.f;
    #pragma unroll
    for (int i = 0; i < 4; i++)
      #pragma unroll
      for (int j = 0; j < 4; j++) {
        const int col = col0 + wc + j * 16 + lo;
        #pragma unroll
        for (int r = 0; r < 4; r++) {
          const float e = __expf(acc[i][j][r]);
          rsum[i][r] += e;
          const int row = row0 + wr + i * 16 + hi * 4 + r;
          outp[(size_t)row * SEQ + col] = f2b(e);
        }
      }
    #pragma unroll
    for (int msk = 1; msk < 16; msk <<= 1)
      #pragma unroll
      for (int i = 0; i < 4; i++)
        #pragma unroll
        for (int r = 0; r < 4; r++)
          rsum[i][r] += __shfl_xor(rsum[i][r], msk, 64);
    if (lo == 0) {
      #pragma unroll
      for (int i = 0; i < 4; i++)
        #pragma unroll
        for (int r = 0; r < 4; r++)
          atomicAdd(&lsum[row0 + wr + i * 16 + hi * 4 + r], rsum[i][r]);
    }
  } else {
    #pragma unroll
    for (int i = 0; i < 4; i++)
      #pragma unroll
      for (int j = 0; j < 4; j++) {
        const int col = col0 + wc + j * 16 + lo;
        #pragma unroll
        for (int r = 0; r < 4; r++) {
          const int row = row0 + wr + i * 16 + hi * 4 + r;
          outp[(size_t)col * CH + row] = f2b(acc[i][j][r] * scale);
        }
      }
  }
}

// ---------------- w[m] += sum_n E[n,m] / l[n]  (softmax column sums) ---------
// grid (R/128, 2): each block does 128 n-rows x 2048 m-cols, 8 m per thread.
__launch_bounds__(256)
__global__ void w_k(const u16* __restrict__ E, const float* __restrict__ l,
                    float* __restrict__ w)
{
  __shared__ float rl[128];
  const int t  = threadIdx.x;
  const int m0 = (blockIdx.y * 256 + t) * 8;
  const int n0 = blockIdx.x * 128;
  if (t < 128) rl[t] = 1.0f / l[n0 + t];
  __syncthreads();
  float acc[8] = {0.f, 0.f, 0.f, 0.f, 0.f, 0.f, 0.f, 0.f};
  for (int n = 0; n < 128; n++) {
    const float r = rl[n];
    union { v8s v; u16 u[8]; } e;
    e.v = *(const v8s*)(E + (size_t)(n0 + n) * SEQ + m0);
    #pragma unroll
    for (int u = 0; u < 8; u++) acc[u] = fmaf(b2f(e.u[u]), r, acc[u]);
  }
  #pragma unroll
  for (int u = 0; u < 8; u++) atomicAdd(&w[m0 + u], acc[u]);
}

// ---------------- s = (1/N) w^T x ; mx = mean_n x ---------------------------
__launch_bounds__(256)
__global__ void sx_k(const float* __restrict__ x, const float* __restrict__ w,
                     float* __restrict__ s, float* __restrict__ mx)
{
  const int b  = blockIdx.x;
  const int c  = blockIdx.y * 256 + threadIdx.x;
  const int m0 = blockIdx.z * 256;
  if (c >= CH) return;
  const float* xb = x + (size_t)b * NC;
  const float* wb = w + b * SEQ;
  float sw = 0.f, sxv = 0.f;
  for (int m = m0; m < m0 + 256; m++) {
    const float xv = xb[(size_t)m * CH + c];
    sw  = fmaf(wb[m], xv, sw);
    sxv += xv;
  }
  const float inv = 1.0f / (float)SEQ;
  atomicAdd(&s[b * CH + c], sw * inv);
  atomicAdd(&mx[b * CH + c], sxv * inv);
}

// ---------------- split-K batched GEMV: outacc[b][col] += EPI(in)[k] W[k][col]
// EPI 0: identity; 1: in+bias+mx (pooled); 2: relu(in+bias)
// grid (7 col-tiles, 8 batches, 7 k-tiles), block 256.
template<int EPI>
__launch_bounds__(256)
__global__ void gemv_k(const float* __restrict__ in, const float* __restrict__ W,
                       const float* __restrict__ bias, const float* __restrict__ mx,
                       float* __restrict__ outacc)
{
  __shared__ float vin[128];
  const int t  = threadIdx.x;
  const int b  = blockIdx.y;
  const int n0 = blockIdx.x * 128;
  const int k0 = blockIdx.z * 128;
  if (t < 128) {
    float v = in[b * CH + k0 + t];
    if constexpr (EPI == 1) v = v + bias[k0 + t] + mx[b * CH + k0 + t];
    if constexpr (EPI == 2) v = fmaxf(v + bias[k0 + t], 0.f);
    vin[t] = v;
  }
  __syncthreads();
  const int col = n0 + (t & 127);
  const int kh  = (t >> 7) * 64;
  const float* wp = W + (size_t)(k0 + kh) * CH + col;
  float acc = 0.f;
  #pragma unroll 8
  for (int i = 0; i < 64; i++)
    acc = fmaf(vin[kh + i], wp[(size_t)i * CH], acc);
  atomicAdd(&outacc[b * CH + col], acc);
}

// ---------------- out[b][e] = bf2[e] (accumulator init for final stage) ------
__global__ void initout_k(const float* __restrict__ bf2, float* __restrict__ out)
{
  out[blockIdx.x * CH + threadIdx.x] = bf2[threadIdx.x];
}

// ---------------- host -------------------------------------------------------
// Workspace layout (floor ~21 MB; E slab adapts to remaining ws):
//   [0,131072)          l_   (8*4096 f32, atomic row sums)        — memset 0
//   [131072,262144)     w_   (8*4096 f32, atomic col sums)        — memset 0
//   [262144,290816)     s_   (8*896 f32)                          — memset 0
//   [290816,319488)     mx_  (8*896 f32)                          — memset 0
//   [319488,348160)     t1_  (8*896 f32, s@Wv accum)              — memset 0
//   [348160,376832)     t2_  (8*896 f32, t1@Wp accum)             — memset 0
//   [376832,405504)     h_   (8*896 f32, pooled@Wf1 accum)        — memset 0
//   [405504,2011136)    wqb  (bf16 Wq)
//   [2011136,3616768)   wkb  (bf16 Wk)
//   [3616768,5222400)   mt   (bf16 M^T, M = scale*Wq@Wk^T)
//   [5222400,12562432)  xb   (bf16 x, ONE batch)
//   [12562432,19902464) yb   (bf16 y = x@M, ONE batch)
//   [19902464,...)      E    (bf16 exp(S) slab, R rows x 4096)
extern "C" void kernel_launch(void* const* d_in, const int* in_sizes, int n_in,
                              void* d_out, int out_size, void* d_ws, size_t ws_size,
                              hipStream_t stream)
{
  (void)in_sizes; (void)n_in; (void)out_size;
  const float* x   = (const float*)d_in[0];
  const float* Wq  = (const float*)d_in[1];
  const float* Wk  = (const float*)d_in[2];
  const float* Wv  = (const float*)d_in[3];
  const float* Wp  = (const float*)d_in[4];
  const float* bp  = (const float*)d_in[5];
  const float* Wf1 = (const float*)d_in[6];
  const float* bf1 = (const float*)d_in[7];
  const float* Wf2 = (const float*)d_in[8];
  const float* bf2 = (const float*)d_in[9];
  float* out = (float*)d_out;

  char* ws = (char*)d_ws;
  float* l_  = (float*)(ws + 0);
  float* w_  = (float*)(ws + 131072);
  float* s_  = (float*)(ws + 262144);
  float* mx_ = (float*)(ws + 290816);
  float* t1_ = (float*)(ws + 319488);
  float* t2_ = (float*)(ws + 348160);
  float* h_  = (float*)(ws + 376832);
  u16* wqb = (u16*)(ws + 405504);
  u16* wkb = (u16*)(ws + 2011136);
  u16* mt  = (u16*)(ws + 3616768);
  u16* xb  = (u16*)(ws + 5222400);
  u16* yb  = (u16*)(ws + 12562432);
  u16* eb  = (u16*)(ws + 19902464);

  // E slab rows: as many 128-row blocks as fit in the remaining workspace
  const size_t ecap = ws_size > 19902464ULL ? ws_size - 19902464ULL : 0;
  int R = (int)(ecap / ((size_t)SEQ * 2) / 128) * 128;
  if (R > SEQ) R = SEQ;
  if (R < 128) R = 128;   // below this we cannot run; assume ws >= ~21MB

  // zero the atomically-accumulated buffers (ws is poisoned before every call)
  hipMemsetAsync(d_ws, 0, 405504, stream);
  initout_k<<<8, 896, 0, stream>>>(bf2, out);

  cvt_k<<<392, 256, 0, stream>>>(Wq, wqb);
  cvt_k<<<392, 256, 0, stream>>>(Wk, wkb);
  const float scale = 1.0f / sqrtf((float)CH);
  // mt = (scale * Wq @ Wk^T)^T
  gemm_k<2><<<dim3(7, 7), 256, 0, stream>>>(wqb, wkb, mt, nullptr, scale);

  for (int b = 0; b < NBATCH; b++) {
    cvt_k<<<1792, 256, 0, stream>>>(x + (size_t)b * NC, xb);
    // y_b = x_b @ M (mt rows are k-contiguous)
    gemm_k<0><<<dim3(32, 7), 256, 0, stream>>>(xb, mt, yb, nullptr, 1.f);
    for (int n0 = 0; n0 < SEQ; n0 += R) {
      const int rows = (SEQ - n0) < R ? (SEQ - n0) : R;
      // E = exp(y_b[n0:n0+rows] @ x_b^T), row sums -> l
      gemm_k<1><<<dim3(rows / 128, 32), 256, 0, stream>>>(
          yb + (size_t)n0 * CH, xb, eb, l_ + b * SEQ + n0, 1.f);
      // w += colsum(E / l)
      w_k<<<dim3(rows / 128, 2), 256, 0, stream>>>(
          eb, l_ + b * SEQ + n0, w_ + b * SEQ);
    }
  }

  sx_k<<<dim3(8, 4, 16), 256, 0, stream>>>(x, w_, s_, mx_);

  // tail: 4 split-K GEMVs, epilogues applied by the consumer stage
  const dim3 gv(7, 8, 7);
  gemv_k<0><<<gv, 256, 0, stream>>>(s_,  Wv,  nullptr, nullptr, t1_);
  gemv_k<0><<<gv, 256, 0, stream>>>(t1_, Wp,  nullptr, nullptr, t2_);
  gemv_k<1><<<gv, 256, 0, stream>>>(t2_, Wf1, bp,      mx_,     h_);
  gemv_k<2><<<gv, 256, 0, stream>>>(h_,  Wf2, bf1,     nullptr, out);
}

// Round 5
// 706.378 us; speedup vs baseline: 1.7435x; 1.3461x over previous
//
#include <hip/hip_runtime.h>
#include <cmath>

typedef unsigned short u16;
typedef __attribute__((ext_vector_type(8))) short v8s;
typedef __attribute__((ext_vector_type(4))) short v4s;
typedef __attribute__((ext_vector_type(4))) float f32x4;

#define NBATCH 8
#define SEQ 4096
#define CH 896
#define NC ((size_t)SEQ * CH)     /* 3670016 elems per batch */
#define NN ((size_t)SEQ * SEQ)    /* 16777216 elems per batch */

__device__ __forceinline__ float b2f(u16 u) {
  unsigned v = ((unsigned)u) << 16;
  return __builtin_bit_cast(float, v);
}
__device__ __forceinline__ u16 f2b(float f) {
  unsigned u = __builtin_bit_cast(unsigned, f);
  u += 0x7FFFu + ((u >> 16) & 1u);   // RNE
  return (u16)(u >> 16);
}

__device__ __forceinline__ f32x4 mfma16(v8s a, v8s b, f32x4 c) {
  asm("v_mfma_f32_16x16x32_bf16 %0, %1, %2, %0" : "+v"(c) : "v"(a), "v"(b));
  return c;
}

// async global->LDS DMA, 16B per lane (global_load_lds_dwordx4)
__device__ __forceinline__ void gload16(const u16* g, u16* l) {
  __builtin_amdgcn_global_load_lds(
      (const __attribute__((address_space(1))) unsigned int*)g,
      (__attribute__((address_space(3))) unsigned int*)l, 16, 0, 0);
}

// ---------------- fp32 -> bf16 convert (8 elems/thread, exact-sized grid) ----
__launch_bounds__(256)
__global__ void cvt_k(const float* __restrict__ in, u16* __restrict__ out)
{
  const size_t i = ((size_t)blockIdx.x * 256 + threadIdx.x) * 8;
  const float4 a = *(const float4*)(in + i);
  const float4 b = *(const float4*)(in + i + 4);
  union { v8s v; u16 u[8]; } o;
  o.u[0] = f2b(a.x); o.u[1] = f2b(a.y); o.u[2] = f2b(a.z); o.u[3] = f2b(a.w);
  o.u[4] = f2b(b.x); o.u[5] = f2b(b.y); o.u[6] = f2b(b.z); o.u[7] = f2b(b.w);
  *(v8s*)(out + i) = o.v;
}

// ---------------- bf16 MFMA NT-GEMM, 128x128 tile, BK=32, 4 waves -----------
// D[i][j] = sum_k A[i][k] * B[j][k]   (both A,B row-major [rows][896])
// Staging via global_load_lds width=16 into LINEAR LDS [128][32] (no pad).
// z-grid batching via element strides az/bz/oz/lz.
// MODE 0: store bf16 D row-major ld=896 (y = x @ M)
// MODE 1: E = exp(D) bf16 ld=4096, atomic row sums -> lsum
// MODE 2: store bf16 scale*D TRANSPOSED ld=896 (mt = (scale*Wq@Wk^T)^T)
template<int MODE>
__launch_bounds__(256)
__global__ void gemm_k(const u16* __restrict__ A, const u16* __restrict__ B,
                       u16* __restrict__ outp, float* __restrict__ lsum, float scale,
                       size_t az, size_t bz, size_t oz, int lz)
{
  __shared__ __align__(16) u16 As[128 * 32];
  __shared__ __align__(16) u16 Bs[128 * 32];
  const int z = blockIdx.z;
  A += (size_t)z * az; B += (size_t)z * bz; outp += (size_t)z * oz;
  if constexpr (MODE == 1) lsum += z * lz;
  const int tid  = threadIdx.x;
  const int lane = tid & 63;
  const int wv   = tid >> 6;
  const int wr   = (wv >> 1) * 64;
  const int wc   = (wv & 1) * 64;
  const int row0 = blockIdx.x * 128;
  const int col0 = blockIdx.y * 128;
  const int srow = tid >> 2;        // 0..63
  const int sk   = (tid & 3) * 8;   // 0,8,16,24
  const u16* ag = A + (size_t)(row0 + srow) * CH + sk;
  const u16* bg = B + (size_t)(col0 + srow) * CH + sk;
  u16* asd = As + tid * 8;          // linear DMA dest: row-major [row][k]
  u16* bsd = Bs + tid * 8;          //   (t*8 == (t>>2)*32 + (t&3)*8)

  f32x4 acc[4][4];
  #pragma unroll
  for (int i = 0; i < 4; i++)
    #pragma unroll
    for (int j = 0; j < 4; j++)
      acc[i][j] = f32x4{0.f, 0.f, 0.f, 0.f};

  const int lo = lane & 15, hi = lane >> 4;
  const int kk = hi * 8;

  for (int k0 = 0; k0 < CH; k0 += 32) {
    __syncthreads();                     // prev tile's ds_reads all consumed
    gload16(ag + k0, asd);
    gload16(ag + (size_t)64 * CH + k0, asd + 64 * 32);
    gload16(bg + k0, bsd);
    gload16(bg + (size_t)64 * CH + k0, bsd + 64 * 32);
    __syncthreads();                     // compiler drains vmcnt before barrier
    v8s af[4], bf[4];
    #pragma unroll
    for (int f = 0; f < 4; f++) af[f] = *(const v8s*)(As + (wr + lo + f * 16) * 32 + kk);
    #pragma unroll
    for (int f = 0; f < 4; f++) bf[f] = *(const v8s*)(Bs + (wc + lo + f * 16) * 32 + kk);
    #pragma unroll
    for (int i = 0; i < 4; i++)
      #pragma unroll
      for (int j = 0; j < 4; j++)
        acc[i][j] = mfma16(af[i], bf[j], acc[i][j]);
  }
  __builtin_amdgcn_sched_barrier(0);
  asm volatile("s_nop 7\ns_nop 7\ns_nop 7");   // MFMA->VALU read hazard guard
  __builtin_amdgcn_sched_barrier(0);

  if constexpr (MODE == 0) {
    #pragma unroll
    for (int i = 0; i < 4; i++)
      #pragma unroll
      for (int j = 0; j < 4; j++) {
        const int col = col0 + wc + j * 16 + lo;
        #pragma unroll
        for (int r = 0; r < 4; r++) {
          const int row = row0 + wr + i * 16 + hi * 4 + r;
          outp[(size_t)row * CH + col] = f2b(acc[i][j][r]);
        }
      }
  } else if constexpr (MODE == 1) {
    float rsum[4][4];
    #pragma unroll
    for (int i = 0; i < 4; i++)
      #pragma unroll
      for (int r = 0; r < 4; r++) rsum[i][r] = 0.f;
    #pragma unroll
    for (int i = 0; i < 4; i++)
      #pragma unroll
      for (int j = 0; j < 4; j++) {
        const int col = col0 + wc + j * 16 + lo;
        #pragma unroll
        for (int r = 0; r < 4; r++) {
          const float e = __expf(acc[i][j][r]);
          rsum[i][r] += e;
          const int row = row0 + wr + i * 16 + hi * 4 + r;
          outp[(size_t)row * SEQ + col] = f2b(e);
        }
      }
    #pragma unroll
    for (int msk = 1; msk < 16; msk <<= 1)
      #pragma unroll
      for (int i = 0; i < 4; i++)
        #pragma unroll
        for (int r = 0; r < 4; r++)
          rsum[i][r] += __shfl_xor(rsum[i][r], msk, 64);
    if (lo == 0) {
      #pragma unroll
      for (int i = 0; i < 4; i++)
        #pragma unroll
        for (int r = 0; r < 4; r++)
          atomicAdd(&lsum[row0 + wr + i * 16 + hi * 4 + r], rsum[i][r]);
    }
  } else {
    #pragma unroll
    for (int i = 0; i < 4; i++)
      #pragma unroll
      for (int j = 0; j < 4; j++) {
        const int col = col0 + wc + j * 16 + lo;
        #pragma unroll
        for (int r = 0; r < 4; r++) {
          const int row = row0 + wr + i * 16 + hi * 4 + r;
          outp[(size_t)col * CH + row] = f2b(acc[i][j][r] * scale);
        }
      }
  }
}

// ---------------- w[m] += sum_n E[n,m] / l[n]  (softmax column sums) ---------
// grid (n-tiles, 4 col-tiles, batches): 4 cols/thread, 8B vector loads.
__launch_bounds__(256)
__global__ void w_k(const u16* __restrict__ E, const float* __restrict__ l,
                    float* __restrict__ w, size_t ez, int lz)
{
  __shared__ float rl[128];
  const int t = threadIdx.x;
  const int z = blockIdx.z;
  E += (size_t)z * ez; l += z * lz; w += z * lz;
  const int n0 = blockIdx.x * 128;
  const int m0 = (blockIdx.y * 256 + t) * 4;
  if (t < 128) rl[t] = 1.0f / l[n0 + t];
  __syncthreads();
  float a0 = 0.f, a1 = 0.f, a2 = 0.f, a3 = 0.f;
  const u16* ep = E + (size_t)n0 * SEQ + m0;
  #pragma unroll 4
  for (int n = 0; n < 128; n++) {
    union { v4s v; u16 u[4]; } e;
    e.v = *(const v4s*)(ep + (size_t)n * SEQ);
    const float r = rl[n];
    a0 = fmaf(b2f(e.u[0]), r, a0);
    a1 = fmaf(b2f(e.u[1]), r, a1);
    a2 = fmaf(b2f(e.u[2]), r, a2);
    a3 = fmaf(b2f(e.u[3]), r, a3);
  }
  atomicAdd(&w[m0 + 0], a0);
  atomicAdd(&w[m0 + 1], a1);
  atomicAdd(&w[m0 + 2], a2);
  atomicAdd(&w[m0 + 3], a3);
}

// ---------------- s = (1/N) w^T x ; mx = mean_n x ---------------------------
__launch_bounds__(256)
__global__ void sx_k(const float* __restrict__ x, const float* __restrict__ w,
                     float* __restrict__ s, float* __restrict__ mx)
{
  const int b  = blockIdx.x;
  const int c  = blockIdx.y * 256 + threadIdx.x;
  const int m0 = blockIdx.z * 256;
  if (c >= CH) return;
  const float* xb = x + (size_t)b * NC;
  const float* wb = w + b * SEQ;
  float sw = 0.f, sxv = 0.f;
  for (int m = m0; m < m0 + 256; m++) {
    const float xv = xb[(size_t)m * CH + c];
    sw  = fmaf(wb[m], xv, sw);
    sxv += xv;
  }
  const float inv = 1.0f / (float)SEQ;
  atomicAdd(&s[b * CH + c], sw * inv);
  atomicAdd(&mx[b * CH + c], sxv * inv);
}

// ---------------- split-K batched GEMV: outacc[b][col] += EPI(in)[k] W[k][col]
// EPI 0: identity; 1: in+bias+mx (pooled); 2: relu(in+bias)
// grid (7 col-tiles, 8 batches, 7 k-tiles), block 256.
template<int EPI>
__launch_bounds__(256)
__global__ void gemv_k(const float* __restrict__ in, const float* __restrict__ W,
                       const float* __restrict__ bias, const float* __restrict__ mx,
                       float* __restrict__ outacc)
{
  __shared__ float vin[128];
  const int t  = threadIdx.x;
  const int b  = blockIdx.y;
  const int n0 = blockIdx.x * 128;
  const int k0 = blockIdx.z * 128;
  if (t < 128) {
    float v = in[b * CH + k0 + t];
    if constexpr (EPI == 1) v = v + bias[k0 + t] + mx[b * CH + k0 + t];
    if constexpr (EPI == 2) v = fmaxf(v + bias[k0 + t], 0.f);
    vin[t] = v;
  }
  __syncthreads();
  const int col = n0 + (t & 127);
  const int kh  = (t >> 7) * 64;
  const float* wp = W + (size_t)(k0 + kh) * CH + col;
  float acc = 0.f;
  #pragma unroll 8
  for (int i = 0; i < 64; i++)
    acc = fmaf(vin[kh + i], wp[(size_t)i * CH], acc);
  atomicAdd(&outacc[b * CH + col], acc);
}

// ---------------- out[b][e] = bf2[e] (accumulator init for final stage) ------
__global__ void initout_k(const float* __restrict__ bf2, float* __restrict__ out)
{
  out[blockIdx.x * CH + threadIdx.x] = bf2[threadIdx.x];
}

// ---------------- host -------------------------------------------------------
// Accumulators (memset 0): [0,405504) = l_ w_ s_ mx_ t1_ t2_ h_
// Weights bf16: wqb@405504 wkb@2011136 mt@3616768 (1605632 B each)
// FULL path (ws >= 391098368 B): xb@5222400 (58720256), yb@63942656 (58720256),
//                                eb@122662912 (268435456)  — all 8 batches.
// FALLBACK (small ws): xb/yb one batch (7340032 B each) @5222400/@12562432,
//                      eb@19902464, E slab R rows adaptive.
extern "C" void kernel_launch(void* const* d_in, const int* in_sizes, int n_in,
                              void* d_out, int out_size, void* d_ws, size_t ws_size,
                              hipStream_t stream)
{
  (void)in_sizes; (void)n_in; (void)out_size;
  const float* x   = (const float*)d_in[0];
  const float* Wq  = (const float*)d_in[1];
  const float* Wk  = (const float*)d_in[2];
  const float* Wv  = (const float*)d_in[3];
  const float* Wp  = (const float*)d_in[4];
  const float* bp  = (const float*)d_in[5];
  const float* Wf1 = (const float*)d_in[6];
  const float* bf1 = (const float*)d_in[7];
  const float* Wf2 = (const float*)d_in[8];
  const float* bf2 = (const float*)d_in[9];
  float* out = (float*)d_out;

  char* ws = (char*)d_ws;
  float* l_  = (float*)(ws + 0);
  float* w_  = (float*)(ws + 131072);
  float* s_  = (float*)(ws + 262144);
  float* mx_ = (float*)(ws + 290816);
  float* t1_ = (float*)(ws + 319488);
  float* t2_ = (float*)(ws + 348160);
  float* h_  = (float*)(ws + 376832);
  u16* wqb = (u16*)(ws + 405504);
  u16* wkb = (u16*)(ws + 2011136);
  u16* mt  = (u16*)(ws + 3616768);
  u16* xb  = (u16*)(ws + 5222400);

  // zero the atomically-accumulated buffers (ws is poisoned before every call)
  hipMemsetAsync(d_ws, 0, 405504, stream);
  initout_k<<<8, 896, 0, stream>>>(bf2, out);

  cvt_k<<<392, 256, 0, stream>>>(Wq, wqb);
  cvt_k<<<392, 256, 0, stream>>>(Wk, wkb);
  const float scale = 1.0f / sqrtf((float)CH);
  // mt = (scale * Wq @ Wk^T)^T
  gemm_k<2><<<dim3(7, 7), 256, 0, stream>>>(wqb, wkb, mt, nullptr, scale, 0, 0, 0, 0);

  if (ws_size >= 391098368ULL) {
    // -------- FULL path: all batches resident, 6 big launches --------
    u16* yb = (u16*)(ws + 63942656ULL);
    u16* eb = (u16*)(ws + 122662912ULL);
    cvt_k<<<14336, 256, 0, stream>>>(x, xb);
    // y = x @ M for all 32768 rows
    gemm_k<0><<<dim3(256, 7), 256, 0, stream>>>(xb, mt, yb, nullptr, 1.f, 0, 0, 0, 0);
    // E = exp(y_b @ x_b^T) per batch (z), row sums -> l
    gemm_k<1><<<dim3(32, 32, NBATCH), 256, 0, stream>>>(yb, xb, eb, l_, 1.f,
                                                        NC, NC, NN, SEQ);
    // w += colsum(E / l)
    w_k<<<dim3(32, 4, NBATCH), 256, 0, stream>>>(eb, l_, w_, NN, SEQ);
  } else {
    // -------- FALLBACK: per-batch loop, E slab adaptive --------
    u16* yb = (u16*)(ws + 12562432);
    u16* eb = (u16*)(ws + 19902464);
    const size_t ecap = ws_size > 19902464ULL ? ws_size - 19902464ULL : 0;
    int R = (int)(ecap / ((size_t)SEQ * 2) / 128) * 128;
    if (R > SEQ) R = SEQ;
    if (R < 128) R = 128;   // below this we cannot run; assume ws >= ~21MB
    for (int b = 0; b < NBATCH; b++) {
      cvt_k<<<1792, 256, 0, stream>>>(x + (size_t)b * NC, xb);
      gemm_k<0><<<dim3(32, 7), 256, 0, stream>>>(xb, mt, yb, nullptr, 1.f, 0, 0, 0, 0);
      for (int n0 = 0; n0 < SEQ; n0 += R) {
        const int rows = (SEQ - n0) < R ? (SEQ - n0) : R;
        gemm_k<1><<<dim3(rows / 128, 32), 256, 0, stream>>>(
            yb + (size_t)n0 * CH, xb, eb, l_ + b * SEQ + n0, 1.f, 0, 0, 0, 0);
        w_k<<<dim3(rows / 128, 4), 256, 0, stream>>>(
            eb, l_ + b * SEQ + n0, w_ + b * SEQ, 0, 0);
      }
    }
  }

  sx_k<<<dim3(8, 4, 16), 256, 0, stream>>>(x, w_, s_, mx_);

  // tail: 4 split-K GEMVs, epilogues applied by the consumer stage
  const dim3 gv(7, 8, 7);
  gemv_k<0><<<gv, 256, 0, stream>>>(s_,  Wv,  nullptr, nullptr, t1_);
  gemv_k<0><<<gv, 256, 0, stream>>>(t1_, Wp,  nullptr, nullptr, t2_);
  gemv_k<1><<<gv, 256, 0, stream>>>(t2_, Wf1, bp,      mx_,     h_);
  gemv_k<2><<<gv, 256, 0, stream>>>(h_,  Wf2, bf1,     nullptr, out);
}